// Round 12
// baseline (703.510 us; speedup 1.0000x reference)
//
#include <hip/hip_runtime.h>
#include <hip/hip_bf16.h>
#include <math.h>

#define HW 3136
#define WIDTH 56
#define CC 256
#define BB 4
#define RCH 32
#define NJT (HW / 64)
#define SCLOG2E 0.2550437041556575f  // (1/sqrt(32)) * log2(e), folded into Q

using bf16x8 = __attribute__((ext_vector_type(8))) short;
using f32x4  = __attribute__((ext_vector_type(4))) float;

static __device__ __forceinline__ unsigned short f2bf(float f) {
    __hip_bfloat16 h = __float2bfloat16(f);
    return *reinterpret_cast<unsigned short*>(&h);
}

// ---------------------------------------------------------------------------
// Fused weight prep: q-conv repacks (Wb[t][r][c]), wproj cast, wk/wq1 cast,
// wv cast. One launch.
// ---------------------------------------------------------------------------
__global__ __launch_bounds__(256) void prep_weights(
    const float* __restrict__ wq3, const float* __restrict__ wq5,
    const float* __restrict__ wq7, const float* __restrict__ wproj,
    const float* __restrict__ wk, const float* __restrict__ wq1,
    const float* __restrict__ wv,
    unsigned short* __restrict__ Wb3, unsigned short* __restrict__ Wb5,
    unsigned short* __restrict__ Wb7, unsigned short* __restrict__ Wpb,
    unsigned short* __restrict__ Wkq, unsigned short* __restrict__ Wvb) {
    int e = blockIdx.x * 256 + threadIdx.x;
    if (e < 73728) {  // wq3: KT=9
        int c = e & 255, r = (e >> 8) & 31, t = e >> 13;
        Wb3[e] = f2bf(wq3[((size_t)r * 256 + c) * 9 + t]);
    } else if (e < 278528) {  // wq5: KT=25
        int i = e - 73728;
        int c = i & 255, r = (i >> 8) & 31, t = i >> 13;
        Wb5[i] = f2bf(wq5[((size_t)r * 256 + c) * 25 + t]);
    } else if (e < 679936) {  // wq7: KT=49
        int i = e - 278528;
        int c = i & 255, r = (i >> 8) & 31, t = i >> 13;
        Wb7[i] = f2bf(wq7[((size_t)r * 256 + c) * 49 + t]);
    } else if (e < 942080) {  // wproj [256][1024]
        int i = e - 679936;
        Wpb[i] = f2bf(wproj[i]);
    } else if (e < 958464) {  // wk | wq1, [2][32][256]
        int i = e - 942080;
        Wkq[i] = f2bf(i < 8192 ? wk[i] : wq1[i - 8192]);
    } else if (e < 1024000) {  // wv [256][256]
        int i = e - 958464;
        Wvb[i] = f2bf(wv[i]);
    }
}

// ---------------------------------------------------------------------------
// x transpose + bf16: xT[b][hw][c]. grid (HW/32, C/32, B), block 256 (32x8).
// ---------------------------------------------------------------------------
__global__ __launch_bounds__(256) void transpose_x(
    const float* __restrict__ x, unsigned short* __restrict__ xT) {
    __shared__ unsigned short tile[32][33];
    const int b = blockIdx.z;
    const int i0 = blockIdx.x * 32, c0 = blockIdx.y * 32;
    const int tx = threadIdx.x & 31, ty = threadIdx.x >> 5;
    #pragma unroll
    for (int k = 0; k < 4; ++k)
        tile[ty + k * 8][tx] = f2bf(x[((size_t)b * CC + c0 + ty + k * 8) * HW + i0 + tx]);
    __syncthreads();
    #pragma unroll
    for (int k = 0; k < 4; ++k)
        xT[((size_t)b * HW + i0 + ty + k * 8) * 256 + c0 + tx] = tile[tx][ty + k * 8];
}

// ---------------------------------------------------------------------------
// K / Q1 via MFMA, no LDS, no barriers. outt[b][hw][32] bf16 (Q pre-scaled).
// grid (HW/64, B, 2): z=0 -> K (scale 1), z=1 -> Q1 (scale SCLOG2E).
// ---------------------------------------------------------------------------
__global__ __launch_bounds__(256) void qk32_mfma(
    const unsigned short* __restrict__ xT, const unsigned short* __restrict__ Wkq,
    unsigned short* __restrict__ Kt, unsigned short* __restrict__ Qt) {
    const int b = blockIdx.y, z = blockIdx.z;
    const int i0 = blockIdx.x * 64;
    const int t = threadIdx.x;
    const int lane = t & 63, w = t >> 6, lg = lane >> 4, li = lane & 15;

    unsigned short* outp = z == 0 ? Kt : Qt;
    const float osc = z == 0 ? 1.0f : SCLOG2E;
    const unsigned short* wb = Wkq + z * 8192;
    const unsigned short* xb = xT + ((size_t)b * HW + i0 + w * 16 + li) * 256;

    const f32x4 z4 = (f32x4){0.f, 0.f, 0.f, 0.f};
    f32x4 acc[2] = {z4, z4};

    for (int c0 = 0; c0 < 256; c0 += 32) {
        bf16x8 ax = *(const bf16x8*)(xb + c0 + lg * 8);
        #pragma unroll
        for (int rs = 0; rs < 2; ++rs) {
            bf16x8 bw = *(const bf16x8*)(wb + (size_t)(rs * 16 + li) * 256 + c0 + lg * 8);
            acc[rs] = __builtin_amdgcn_mfma_f32_16x16x32_bf16(ax, bw, acc[rs], 0, 0, 0);
        }
    }
    unsigned short* qb = outp + ((size_t)b * HW + i0 + w * 16 + lg * 4) * 32;
    #pragma unroll
    for (int rs = 0; rs < 2; ++rs)
        #pragma unroll
        for (int r = 0; r < 4; ++r)
            qb[(size_t)r * 32 + rs * 16 + li] = f2bf(acc[rs][r] * osc);
}

// ---------------------------------------------------------------------------
// V via MFMA, no LDS, no barriers. V[b][co][hw] bf16.
// grid (HW/32, B). Wave w owns co strip w*64..+63.
// ---------------------------------------------------------------------------
__global__ __launch_bounds__(256) void v_mfma(
    const unsigned short* __restrict__ xT, const unsigned short* __restrict__ Wvb,
    unsigned short* __restrict__ Vb) {
    const int b = blockIdx.y;
    const int i0 = blockIdx.x * 32;
    const int t = threadIdx.x;
    const int lane = t & 63, w = t >> 6, lg = lane >> 4, li = lane & 15;

    const f32x4 z4 = (f32x4){0.f, 0.f, 0.f, 0.f};
    f32x4 acc[4][2];
    #pragma unroll
    for (int ct = 0; ct < 4; ++ct) { acc[ct][0] = z4; acc[ct][1] = z4; }

    const unsigned short* xb = xT + (size_t)b * HW * 256;

    for (int c0 = 0; c0 < 256; c0 += 32) {
        bf16x8 bx[2];
        #pragma unroll
        for (int is = 0; is < 2; ++is)
            bx[is] = *(const bf16x8*)(xb + (size_t)(i0 + is * 16 + li) * 256 + c0 + lg * 8);
        #pragma unroll
        for (int ct = 0; ct < 4; ++ct) {
            bf16x8 aw = *(const bf16x8*)(
                Wvb + (size_t)(w * 64 + ct * 16 + li) * 256 + c0 + lg * 8);
            #pragma unroll
            for (int is = 0; is < 2; ++is)
                acc[ct][is] = __builtin_amdgcn_mfma_f32_16x16x32_bf16(
                    aw, bx[is], acc[ct][is], 0, 0, 0);
        }
    }
    #pragma unroll
    for (int ct = 0; ct < 4; ++ct)
        #pragma unroll
        for (int is = 0; is < 2; ++is)
            #pragma unroll
            for (int r = 0; r < 4; ++r)
                Vb[((size_t)b * CC + w * 64 + ct * 16 + lg * 4 + r) * HW +
                   i0 + is * 16 + li] = f2bf(acc[ct][is][r]);
}

// ---------------------------------------------------------------------------
// MFMA im2col q-conv body (shared LDS passed in). Output scaled by SCLOG2E.
// ---------------------------------------------------------------------------
template <int KS>
static __device__ __forceinline__ void qconv_body(
    const unsigned short* __restrict__ xT,  // [b][hw][256] bf16
    const unsigned short* __restrict__ Wb,  // [KT][32][256] bf16
    unsigned short* __restrict__ q,         // [b][hw][32] bf16
    unsigned short (*xs)[40]) {
    constexpr int P = (KS - 1) / 2;
    constexpr int KT = KS * KS;
    constexpr int ROWS = 64 + 114 * P;
    const int b = blockIdx.y;
    const int i0 = blockIdx.x * 64;
    const int t = threadIdx.x;
    const int lane = t & 63;
    const int w = t >> 6;
    const int li = lane & 15;
    const int lg = lane >> 4;

    const int base = i0 - P * 57;
    const int mycol = (i0 + w * 16 + li) % WIDTH;

    f32x4 acc[2];
    acc[0] = (f32x4){0.f, 0.f, 0.f, 0.f};
    acc[1] = (f32x4){0.f, 0.f, 0.f, 0.f};

    const unsigned short* xTb = xT + (size_t)b * HW * 256;

    for (int c0 = 0; c0 < 256; c0 += 32) {
        __syncthreads();
        for (int e = t; e < ROWS * 4; e += 256) {
            int row = e >> 2, cs = e & 3;
            int gidx = base + row;
            uint4 val = make_uint4(0, 0, 0, 0);
            if (gidx >= 0 && gidx < HW)
                val = *(const uint4*)(xTb + (size_t)gidx * 256 + c0 + cs * 8);
            *(uint4*)(&xs[row][cs * 8]) = val;
        }
        __syncthreads();

        #pragma unroll
        for (int tap = 0; tap < KT; ++tap) {
            const int dx = tap % KS - P;
            const int poff = (tap / KS) * WIDTH + tap % KS;
            bf16x8 a = *(const bf16x8*)(&xs[w * 16 + li + poff][lg * 8]);
            if ((unsigned)(mycol + dx) >= (unsigned)WIDTH)
                a = (bf16x8){0, 0, 0, 0, 0, 0, 0, 0};
            const unsigned short* wrow =
                Wb + (size_t)tap * 32 * 256 + c0 + lg * 8;
            bf16x8 b0 = *(const bf16x8*)(wrow + (size_t)li * 256);
            bf16x8 b1 = *(const bf16x8*)(wrow + (size_t)(16 + li) * 256);
            acc[0] = __builtin_amdgcn_mfma_f32_16x16x32_bf16(a, b0, acc[0], 0, 0, 0);
            acc[1] = __builtin_amdgcn_mfma_f32_16x16x32_bf16(a, b1, acc[1], 0, 0, 0);
        }
    }

    unsigned short* qb = q + ((size_t)b * HW + i0 + w * 16 + lg * 4) * 32;
    #pragma unroll
    for (int rs = 0; rs < 2; ++rs)
        #pragma unroll
        for (int r = 0; r < 4; ++r)
            qb[(size_t)r * 32 + rs * 16 + li] = f2bf(acc[rs][r] * SCLOG2E);
}

// All three q-convs in one launch: grid (HW/64, B, 3), z picks kernel size.
__global__ __launch_bounds__(256) void qconv_all(
    const unsigned short* __restrict__ xT,
    const unsigned short* __restrict__ Wb3,
    const unsigned short* __restrict__ Wb5,
    const unsigned short* __restrict__ Wb7,
    unsigned short* __restrict__ Qt) {
    __shared__ unsigned short xs[406][40];  // sized for KS=7
    const size_t QSLICE = (size_t)BB * HW * 32;
    if (blockIdx.z == 0)      qconv_body<3>(xT, Wb3, Qt + 1 * QSLICE, xs);
    else if (blockIdx.z == 1) qconv_body<5>(xT, Wb5, Qt + 2 * QSLICE, xs);
    else                      qconv_body<7>(xT, Wb7, Qt + 3 * QSLICE, xs);
}

// ---------------------------------------------------------------------------
// MFMA flash attention, v4: BARRIER-FREE. Swapped QK (mfma(K,Q) -> S^T) puts
// each softmax row lane-local: lane (li,lg) holds P[j=j2*16+lg*4+r][i=li].
// PV exploits MFMA's k-permutation freedom: B-fragment uses P in the permuted
// j-order the lane already holds (quads j2*16+lg*4..+3), and V (A-operand) is
// loaded with the MATCHING quad order (two 8B loads per fragment). P never
// leaves the lane: zero LDS, zero barriers, zero shuffles in the loop.
// Each wave redundantly computes QK for all 64 i (cheap) and owns c-strip
// w*64..+63. lsum reduced once at the end via shfl_xor(16/32).
// grid: (HW/64, B, 4), block 256 (4 independent waves).
// ---------------------------------------------------------------------------
__global__ __launch_bounds__(256) void flashmfma(
    const unsigned short* __restrict__ Qt, const unsigned short* __restrict__ Kt,
    const unsigned short* __restrict__ Vb, unsigned short* __restrict__ ATTb) {
    const int b = blockIdx.y, g = blockIdx.z;
    const int i0 = blockIdx.x * 64;
    const int t = threadIdx.x;
    const int lane = t & 63;
    const int w = t >> 6;
    const int lg = lane >> 4;
    const int li = lane & 15;

    const f32x4 z4 = (f32x4){0.f, 0.f, 0.f, 0.f};

    // Q fragments for all 4 i-strips (loop-invariant, pre-scaled)
    bf16x8 bq[4];
    #pragma unroll
    for (int is = 0; is < 4; ++is)
        bq[is] = *(const bf16x8*)(
            Qt + ((size_t)(g * BB + b) * HW + i0 + is * 16 + li) * 32 + lg * 8);

    f32x4 acc[4][4];  // [ct][is]
    #pragma unroll
    for (int ct = 0; ct < 4; ++ct)
        #pragma unroll
        for (int is = 0; is < 4; ++is) acc[ct][is] = z4;

    float lsum[4] = {0.f, 0.f, 0.f, 0.f};  // partial: this lane's lg-quarter of j

    const unsigned short* Kb = Kt + (size_t)b * HW * 32;
    const unsigned short* Vw = Vb + ((size_t)b * CC + w * 64) * HW;

    for (int jt = 0; jt < NJT; ++jt) {
        const int j0 = jt * 64;

        // ---- K fragments for this tile
        bf16x8 bk[4];
        #pragma unroll
        for (int j2 = 0; j2 < 4; ++j2)
            bk[j2] = *(const bf16x8*)(Kb + (size_t)(j0 + j2 * 16 + li) * 32 + lg * 8);

        // ---- swapped QK^T + softmax, fully in-lane
        // wds[is][2*j2+h] = bf16 pair (p[j2][2h], p[j2][2h+1]) for i=is*16+li
        unsigned int wds[4][8];
        #pragma unroll
        for (int is = 0; is < 4; ++is) {
            f32x4 S[4];
            #pragma unroll
            for (int j2 = 0; j2 < 4; ++j2)
                S[j2] = __builtin_amdgcn_mfma_f32_16x16x32_bf16(bk[j2], bq[is], z4, 0, 0, 0);
            #pragma unroll
            for (int j2 = 0; j2 < 4; ++j2) {
                float p0 = __builtin_amdgcn_exp2f(S[j2][0]);
                float p1 = __builtin_amdgcn_exp2f(S[j2][1]);
                float p2 = __builtin_amdgcn_exp2f(S[j2][2]);
                float p3 = __builtin_amdgcn_exp2f(S[j2][3]);
                lsum[is] += (p0 + p1) + (p2 + p3);
                asm("v_cvt_pk_bf16_f32 %0, %1, %2" : "=v"(wds[is][2 * j2]) : "v"(p0), "v"(p1));
                asm("v_cvt_pk_bf16_f32 %0, %1, %2" : "=v"(wds[is][2 * j2 + 1]) : "v"(p2), "v"(p3));
            }
        }

        // ---- PV with matched permuted-j quad order
        #pragma unroll
        for (int ct = 0; ct < 4; ++ct) {
            const unsigned short* vr = Vw + (size_t)(ct * 16 + li) * HW + j0;
            #pragma unroll
            for (int ks = 0; ks < 2; ++ks) {
                union { uint2 d2[2]; bf16x8 v; } va;
                va.d2[0] = *(const uint2*)(vr + ks * 32 + lg * 4);       // j=32ks+lg*4..+3
                va.d2[1] = *(const uint2*)(vr + ks * 32 + 16 + lg * 4);  // j=32ks+16+lg*4..+3
                #pragma unroll
                for (int is = 0; is < 4; ++is) {
                    union { unsigned int u[4]; bf16x8 v; } pb;
                    pb.u[0] = wds[is][4 * ks + 0];
                    pb.u[1] = wds[is][4 * ks + 1];
                    pb.u[2] = wds[is][4 * ks + 2];
                    pb.u[3] = wds[is][4 * ks + 3];
                    acc[ct][is] = __builtin_amdgcn_mfma_f32_16x16x32_bf16(
                        va.v, pb.v, acc[ct][is], 0, 0, 0);
                }
            }
        }
    }

    // ---- finalize: reduce lsum across the 4 lg groups (lanes li,li+16,li+32,li+48)
    float invl[4];
    #pragma unroll
    for (int is = 0; is < 4; ++is) {
        float s = lsum[is];
        s += __shfl_xor(s, 16);
        s += __shfl_xor(s, 32);
        invl[is] = 1.f / s;
    }

    #pragma unroll
    for (int ct = 0; ct < 4; ++ct)
        #pragma unroll
        for (int is = 0; is < 4; ++is)
            #pragma unroll
            for (int r = 0; r < 4; ++r) {
                int c = w * 64 + ct * 16 + lg * 4 + r;
                ATTb[((size_t)b * (4 * CC) + g * CC + c) * HW + i0 + is * 16 + li] =
                    f2bf(acc[ct][is][r] * invl[is]);
            }
}

// ---------------------------------------------------------------------------
// MFMA projection: out[b][co][i] = sum_{cin<1024} wproj[co][cin]*ATT[cin][i]+x.
// grid (HW/32, B), block 256 (4 waves, wave = 64-co strip).
// ---------------------------------------------------------------------------
__global__ __launch_bounds__(256) void gemm_proj(
    const unsigned short* __restrict__ ATTb, const unsigned short* __restrict__ Wpb,
    const float* __restrict__ x, float* __restrict__ out) {
    const int b = blockIdx.y;
    const int i0 = blockIdx.x * 32;
    const int t = threadIdx.x;
    const int lane = t & 63;
    const int w = t >> 6;
    const int lg = lane >> 4;
    const int li = lane & 15;

    __shared__ __align__(16) unsigned short As[32][72];  // [i][cin-chunk]

    const f32x4 z4 = (f32x4){0.f, 0.f, 0.f, 0.f};
    f32x4 acc[4][2];
    #pragma unroll
    for (int ct = 0; ct < 4; ++ct) { acc[ct][0] = z4; acc[ct][1] = z4; }

    for (int k0 = 0; k0 < 1024; k0 += 64) {
        __syncthreads();
        {
            int row = t >> 2, seg = t & 3;
            uint4 v = *(const uint4*)(
                ATTb + ((size_t)b * 1024 + k0 + row) * HW + i0 + seg * 8);
            const unsigned short* sv = (const unsigned short*)&v;
            #pragma unroll
            for (int u = 0; u < 8; ++u) As[seg * 8 + u][row] = sv[u];
        }
        __syncthreads();

        #pragma unroll
        for (int k2 = 0; k2 < 2; ++k2) {
            bf16x8 afr[2];
            #pragma unroll
            for (int is = 0; is < 2; ++is)
                afr[is] = *(const bf16x8*)(&As[is * 16 + li][k2 * 32 + lg * 8]);
            #pragma unroll
            for (int ct = 0; ct < 4; ++ct) {
                bf16x8 wf = *(const bf16x8*)(
                    Wpb + (size_t)(w * 64 + ct * 16 + li) * 1024 + k0 + k2 * 32 + lg * 8);
                #pragma unroll
                for (int is = 0; is < 2; ++is)
                    acc[ct][is] = __builtin_amdgcn_mfma_f32_16x16x32_bf16(
                        wf, afr[is], acc[ct][is], 0, 0, 0);
            }
        }
    }

    #pragma unroll
    for (int ct = 0; ct < 4; ++ct)
        #pragma unroll
        for (int is = 0; is < 2; ++is)
            #pragma unroll
            for (int r = 0; r < 4; ++r) {
                int co = w * 64 + ct * 16 + lg * 4 + r;
                size_t o = ((size_t)b * CC + co) * HW + i0 + is * 16 + li;
                out[o] = acc[ct][is][r] + x[o];
            }
}

// ---------------------------------------------------------------------------
// BatchNorm
// ---------------------------------------------------------------------------
__global__ __launch_bounds__(256) void bnstats(
    const float* __restrict__ out, float* __restrict__ mean,
    float* __restrict__ rstd) {
    const int c = blockIdx.x;
    float s = 0.f, s2 = 0.f;
    for (int e = threadIdx.x; e < BB * HW; e += 256) {
        int b = e / HW, i = e - b * HW;
        float v = out[((size_t)b * CC + c) * HW + i];
        s += v; s2 += v * v;
    }
    __shared__ float rs[256], rs2[256];
    rs[threadIdx.x] = s; rs2[threadIdx.x] = s2;
    __syncthreads();
    for (int st = 128; st > 0; st >>= 1) {
        if (threadIdx.x < st) {
            rs[threadIdx.x] += rs[threadIdx.x + st];
            rs2[threadIdx.x] += rs2[threadIdx.x + st];
        }
        __syncthreads();
    }
    if (threadIdx.x == 0) {
        const float n = (float)(BB * HW);
        float m = rs[0] / n;
        float var = rs2[0] / n - m * m;
        mean[c] = m;
        rstd[c] = rsqrtf(var + 1e-5f);
    }
}

__global__ __launch_bounds__(256) void bnapply(
    float* __restrict__ out, const float* __restrict__ mean,
    const float* __restrict__ rstd, const float* __restrict__ gamma,
    const float* __restrict__ beta) {
    size_t idx = (size_t)blockIdx.x * 256 + threadIdx.x;
    if (idx < (size_t)BB * CC * HW) {
        int c = (int)((idx / HW) % CC);
        out[idx] = (out[idx] - mean[c]) * rstd[c] * gamma[c] + beta[c];
    }
}

// ---------------------------------------------------------------------------
extern "C" void kernel_launch(void* const* d_in, const int* in_sizes, int n_in,
                              void* d_out, int out_size, void* d_ws, size_t ws_size,
                              hipStream_t stream) {
    const float* x     = (const float*)d_in[0];
    const float* wq1   = (const float*)d_in[1];
    const float* wq3   = (const float*)d_in[2];
    const float* wq5   = (const float*)d_in[3];
    const float* wq7   = (const float*)d_in[4];
    const float* wk    = (const float*)d_in[5];
    const float* wv    = (const float*)d_in[6];
    const float* wproj = (const float*)d_in[7];
    const float* gamma = (const float*)d_in[8];
    const float* beta  = (const float*)d_in[9];
    float* out = (float*)d_out;

    unsigned short* ATTb = (unsigned short*)d_ws;            // [B][1024][HW]
    unsigned short* Kt   = ATTb + (size_t)BB * 4 * CC * HW;  // [B][HW][32]
    unsigned short* Qt   = Kt + (size_t)BB * HW * 32;        // 4 x [B][HW][32]
    unsigned short* Vb   = Qt + (size_t)4 * BB * HW * 32;    // [B][C][HW]
    unsigned short* xT   = Vb + (size_t)BB * CC * HW;        // [B][HW][256]
    unsigned short* Wb3  = xT + (size_t)BB * HW * CC;        // [9][32][256]
    unsigned short* Wb5  = Wb3 + (size_t)9 * 32 * 256;
    unsigned short* Wb7  = Wb5 + (size_t)25 * 32 * 256;
    unsigned short* Wpb  = Wb7 + (size_t)49 * 32 * 256;      // [256][1024]
    unsigned short* Wkq  = Wpb + (size_t)256 * 1024;         // [2][32][256]
    unsigned short* Wvb  = Wkq + (size_t)2 * 32 * 256;       // [256][256]
    float* mean = (float*)(Wvb + (size_t)256 * 256);
    float* rstd = mean + CC;

    dim3 blk(256);

    // prep: all weights (one launch) + x transpose
    prep_weights<<<dim3(4000), blk, 0, stream>>>(
        wq3, wq5, wq7, wproj, wk, wq1, wv, Wb3, Wb5, Wb7, Wpb, Wkq, Wvb);
    transpose_x<<<dim3(HW / 32, CC / 32, BB), blk, 0, stream>>>(x, xT);

    // K + Q1 (MFMA, no LDS), V (MFMA, no LDS)
    qk32_mfma<<<dim3(HW / 64, BB, 2), blk, 0, stream>>>(xT, Wkq, Kt, Qt);
    v_mfma<<<dim3(HW / 32, BB), blk, 0, stream>>>(xT, Wvb, Vb);

    // q3/q5/q7 fused MFMA im2col convs
    qconv_all<<<dim3(HW / 64, BB, 3), blk, 0, stream>>>(xT, Wb3, Wb5, Wb7, Qt);

    // MFMA flash attention v4 (barrier-free, in-lane P), all 4 branches
    flashmfma<<<dim3(HW / 64, BB, 4), blk, 0, stream>>>(Qt, Kt, Vb, ATTb);

    // MFMA projection + residual -> d_out (pre-BN, fp32)
    gemm_proj<<<dim3(HW / 32, BB), blk, 0, stream>>>(ATTb, Wpb, x, out);

    // BatchNorm
    bnstats<<<dim3(CC), blk, 0, stream>>>(out, mean, rstd);
    bnapply<<<dim3((BB * CC * HW + 255) / 256), blk, 0, stream>>>(out, mean, rstd, gamma, beta);
}

// Round 13
// 482.268 us; speedup vs baseline: 1.4588x; 1.4588x over previous
//
#include <hip/hip_runtime.h>
#include <hip/hip_bf16.h>
#include <math.h>

#define HW 3136
#define WIDTH 56
#define CC 256
#define BB 4
#define RCH 32
#define NJT (HW / 64)
#define SCLOG2E 0.2550437041556575f  // (1/sqrt(32)) * log2(e), folded into Q

using bf16x8 = __attribute__((ext_vector_type(8))) short;
using f32x4  = __attribute__((ext_vector_type(4))) float;

static __device__ __forceinline__ unsigned short f2bf(float f) {
    __hip_bfloat16 h = __float2bfloat16(f);
    return *reinterpret_cast<unsigned short*>(&h);
}

// ---------------------------------------------------------------------------
// Fused weight prep: q-conv repacks (Wb[t][r][c]), wproj cast, wk/wq1 cast,
// wv cast. One launch.
// ---------------------------------------------------------------------------
__global__ __launch_bounds__(256) void prep_weights(
    const float* __restrict__ wq3, const float* __restrict__ wq5,
    const float* __restrict__ wq7, const float* __restrict__ wproj,
    const float* __restrict__ wk, const float* __restrict__ wq1,
    const float* __restrict__ wv,
    unsigned short* __restrict__ Wb3, unsigned short* __restrict__ Wb5,
    unsigned short* __restrict__ Wb7, unsigned short* __restrict__ Wpb,
    unsigned short* __restrict__ Wkq, unsigned short* __restrict__ Wvb) {
    int e = blockIdx.x * 256 + threadIdx.x;
    if (e < 73728) {  // wq3: KT=9
        int c = e & 255, r = (e >> 8) & 31, t = e >> 13;
        Wb3[e] = f2bf(wq3[((size_t)r * 256 + c) * 9 + t]);
    } else if (e < 278528) {  // wq5: KT=25
        int i = e - 73728;
        int c = i & 255, r = (i >> 8) & 31, t = i >> 13;
        Wb5[i] = f2bf(wq5[((size_t)r * 256 + c) * 25 + t]);
    } else if (e < 679936) {  // wq7: KT=49
        int i = e - 278528;
        int c = i & 255, r = (i >> 8) & 31, t = i >> 13;
        Wb7[i] = f2bf(wq7[((size_t)r * 256 + c) * 49 + t]);
    } else if (e < 942080) {  // wproj [256][1024]
        int i = e - 679936;
        Wpb[i] = f2bf(wproj[i]);
    } else if (e < 958464) {  // wk | wq1, [2][32][256]
        int i = e - 942080;
        Wkq[i] = f2bf(i < 8192 ? wk[i] : wq1[i - 8192]);
    } else if (e < 1024000) {  // wv [256][256]
        int i = e - 958464;
        Wvb[i] = f2bf(wv[i]);
    }
}

// ---------------------------------------------------------------------------
// x transpose + bf16: xT[b][hw][c]. grid (HW/32, C/32, B), block 256 (32x8).
// ---------------------------------------------------------------------------
__global__ __launch_bounds__(256) void transpose_x(
    const float* __restrict__ x, unsigned short* __restrict__ xT) {
    __shared__ unsigned short tile[32][33];
    const int b = blockIdx.z;
    const int i0 = blockIdx.x * 32, c0 = blockIdx.y * 32;
    const int tx = threadIdx.x & 31, ty = threadIdx.x >> 5;
    #pragma unroll
    for (int k = 0; k < 4; ++k)
        tile[ty + k * 8][tx] = f2bf(x[((size_t)b * CC + c0 + ty + k * 8) * HW + i0 + tx]);
    __syncthreads();
    #pragma unroll
    for (int k = 0; k < 4; ++k)
        xT[((size_t)b * HW + i0 + ty + k * 8) * 256 + c0 + tx] = tile[tx][ty + k * 8];
}

// ---------------------------------------------------------------------------
// K / Q1 via MFMA, no LDS, no barriers. outt[b][hw][32] bf16 (Q pre-scaled).
// grid (HW/64, B, 2): z=0 -> K (scale 1), z=1 -> Q1 (scale SCLOG2E).
// ---------------------------------------------------------------------------
__global__ __launch_bounds__(256) void qk32_mfma(
    const unsigned short* __restrict__ xT, const unsigned short* __restrict__ Wkq,
    unsigned short* __restrict__ Kt, unsigned short* __restrict__ Qt) {
    const int b = blockIdx.y, z = blockIdx.z;
    const int i0 = blockIdx.x * 64;
    const int t = threadIdx.x;
    const int lane = t & 63, w = t >> 6, lg = lane >> 4, li = lane & 15;

    unsigned short* outp = z == 0 ? Kt : Qt;
    const float osc = z == 0 ? 1.0f : SCLOG2E;
    const unsigned short* wb = Wkq + z * 8192;
    const unsigned short* xb = xT + ((size_t)b * HW + i0 + w * 16 + li) * 256;

    const f32x4 z4 = (f32x4){0.f, 0.f, 0.f, 0.f};
    f32x4 acc[2] = {z4, z4};

    for (int c0 = 0; c0 < 256; c0 += 32) {
        bf16x8 ax = *(const bf16x8*)(xb + c0 + lg * 8);
        #pragma unroll
        for (int rs = 0; rs < 2; ++rs) {
            bf16x8 bw = *(const bf16x8*)(wb + (size_t)(rs * 16 + li) * 256 + c0 + lg * 8);
            acc[rs] = __builtin_amdgcn_mfma_f32_16x16x32_bf16(ax, bw, acc[rs], 0, 0, 0);
        }
    }
    unsigned short* qb = outp + ((size_t)b * HW + i0 + w * 16 + lg * 4) * 32;
    #pragma unroll
    for (int rs = 0; rs < 2; ++rs)
        #pragma unroll
        for (int r = 0; r < 4; ++r)
            qb[(size_t)r * 32 + rs * 16 + li] = f2bf(acc[rs][r] * osc);
}

// ---------------------------------------------------------------------------
// V via MFMA, no LDS, no barriers. V[b][co][hw] bf16.
// grid (HW/32, B). Wave w owns co strip w*64..+63.
// ---------------------------------------------------------------------------
__global__ __launch_bounds__(256) void v_mfma(
    const unsigned short* __restrict__ xT, const unsigned short* __restrict__ Wvb,
    unsigned short* __restrict__ Vb) {
    const int b = blockIdx.y;
    const int i0 = blockIdx.x * 32;
    const int t = threadIdx.x;
    const int lane = t & 63, w = t >> 6, lg = lane >> 4, li = lane & 15;

    const f32x4 z4 = (f32x4){0.f, 0.f, 0.f, 0.f};
    f32x4 acc[4][2];
    #pragma unroll
    for (int ct = 0; ct < 4; ++ct) { acc[ct][0] = z4; acc[ct][1] = z4; }

    const unsigned short* xb = xT + (size_t)b * HW * 256;

    for (int c0 = 0; c0 < 256; c0 += 32) {
        bf16x8 bx[2];
        #pragma unroll
        for (int is = 0; is < 2; ++is)
            bx[is] = *(const bf16x8*)(xb + (size_t)(i0 + is * 16 + li) * 256 + c0 + lg * 8);
        #pragma unroll
        for (int ct = 0; ct < 4; ++ct) {
            bf16x8 aw = *(const bf16x8*)(
                Wvb + (size_t)(w * 64 + ct * 16 + li) * 256 + c0 + lg * 8);
            #pragma unroll
            for (int is = 0; is < 2; ++is)
                acc[ct][is] = __builtin_amdgcn_mfma_f32_16x16x32_bf16(
                    aw, bx[is], acc[ct][is], 0, 0, 0);
        }
    }
    #pragma unroll
    for (int ct = 0; ct < 4; ++ct)
        #pragma unroll
        for (int is = 0; is < 2; ++is)
            #pragma unroll
            for (int r = 0; r < 4; ++r)
                Vb[((size_t)b * CC + w * 64 + ct * 16 + lg * 4 + r) * HW +
                   i0 + is * 16 + li] = f2bf(acc[ct][is][r]);
}

// ---------------------------------------------------------------------------
// MFMA im2col q-conv body (shared LDS passed in). Output scaled by SCLOG2E.
// ---------------------------------------------------------------------------
template <int KS>
static __device__ __forceinline__ void qconv_body(
    const unsigned short* __restrict__ xT,  // [b][hw][256] bf16
    const unsigned short* __restrict__ Wb,  // [KT][32][256] bf16
    unsigned short* __restrict__ q,         // [b][hw][32] bf16
    unsigned short (*xs)[40]) {
    constexpr int P = (KS - 1) / 2;
    constexpr int KT = KS * KS;
    constexpr int ROWS = 64 + 114 * P;
    const int b = blockIdx.y;
    const int i0 = blockIdx.x * 64;
    const int t = threadIdx.x;
    const int lane = t & 63;
    const int w = t >> 6;
    const int li = lane & 15;
    const int lg = lane >> 4;

    const int base = i0 - P * 57;
    const int mycol = (i0 + w * 16 + li) % WIDTH;

    f32x4 acc[2];
    acc[0] = (f32x4){0.f, 0.f, 0.f, 0.f};
    acc[1] = (f32x4){0.f, 0.f, 0.f, 0.f};

    const unsigned short* xTb = xT + (size_t)b * HW * 256;

    for (int c0 = 0; c0 < 256; c0 += 32) {
        __syncthreads();
        for (int e = t; e < ROWS * 4; e += 256) {
            int row = e >> 2, cs = e & 3;
            int gidx = base + row;
            uint4 val = make_uint4(0, 0, 0, 0);
            if (gidx >= 0 && gidx < HW)
                val = *(const uint4*)(xTb + (size_t)gidx * 256 + c0 + cs * 8);
            *(uint4*)(&xs[row][cs * 8]) = val;
        }
        __syncthreads();

        #pragma unroll
        for (int tap = 0; tap < KT; ++tap) {
            const int dx = tap % KS - P;
            const int poff = (tap / KS) * WIDTH + tap % KS;
            bf16x8 a = *(const bf16x8*)(&xs[w * 16 + li + poff][lg * 8]);
            if ((unsigned)(mycol + dx) >= (unsigned)WIDTH)
                a = (bf16x8){0, 0, 0, 0, 0, 0, 0, 0};
            const unsigned short* wrow =
                Wb + (size_t)tap * 32 * 256 + c0 + lg * 8;
            bf16x8 b0 = *(const bf16x8*)(wrow + (size_t)li * 256);
            bf16x8 b1 = *(const bf16x8*)(wrow + (size_t)(16 + li) * 256);
            acc[0] = __builtin_amdgcn_mfma_f32_16x16x32_bf16(a, b0, acc[0], 0, 0, 0);
            acc[1] = __builtin_amdgcn_mfma_f32_16x16x32_bf16(a, b1, acc[1], 0, 0, 0);
        }
    }

    unsigned short* qb = q + ((size_t)b * HW + i0 + w * 16 + lg * 4) * 32;
    #pragma unroll
    for (int rs = 0; rs < 2; ++rs)
        #pragma unroll
        for (int r = 0; r < 4; ++r)
            qb[(size_t)r * 32 + rs * 16 + li] = f2bf(acc[rs][r] * SCLOG2E);
}

// All three q-convs in one launch: grid (HW/64, B, 3), z picks kernel size.
__global__ __launch_bounds__(256) void qconv_all(
    const unsigned short* __restrict__ xT,
    const unsigned short* __restrict__ Wb3,
    const unsigned short* __restrict__ Wb5,
    const unsigned short* __restrict__ Wb7,
    unsigned short* __restrict__ Qt) {
    __shared__ unsigned short xs[406][40];  // sized for KS=7
    const size_t QSLICE = (size_t)BB * HW * 32;
    if (blockIdx.z == 0)      qconv_body<3>(xT, Wb3, Qt + 1 * QSLICE, xs);
    else if (blockIdx.z == 1) qconv_body<5>(xT, Wb5, Qt + 2 * QSLICE, xs);
    else                      qconv_body<7>(xT, Wb7, Qt + 3 * QSLICE, xs);
}

// ---------------------------------------------------------------------------
// MFMA flash attention, v5: r11 work partition (wave: QK/softmax on i-strip
// w*16..+15, PV on c-strip w*64..+63; P via LDS) with TWO j-tiles amortized
// per barrier pair: QK+softmax(a), QK+softmax(b) -> B1 -> write both P halves
// (Ps[128][72], tile b in rows 64..127; 144B row stride kept) -> B2 ->
// PV(a), PV(b). Barriers per tile halved vs r11. V fragments for both tiles
// loaded at iteration top (within-iteration hoist, the r11 win). NJT=49 odd:
// 24 pairs + 1 single-tile tail. Accumulation order per element unchanged ->
// bit-identical to r11.
// grid: (HW/64, B, 4), block 256 (4 waves).
// ---------------------------------------------------------------------------
__global__ __launch_bounds__(256) void flashmfma(
    const unsigned short* __restrict__ Qt, const unsigned short* __restrict__ Kt,
    const unsigned short* __restrict__ Vb, unsigned short* __restrict__ ATTb) {
    const int b = blockIdx.y, g = blockIdx.z;
    const int i0 = blockIdx.x * 64;
    const int t = threadIdx.x;
    const int lane = t & 63;
    const int w = t >> 6;
    const int lg = lane >> 4;
    const int li = lane & 15;

    __shared__ __align__(16) unsigned short Ps[128][72];  // 144B rows; b-half rows 64+
    __shared__ float lls[64];

    const bf16x8 aq = *(const bf16x8*)(
        Qt + ((size_t)(g * BB + b) * HW + i0 + w * 16 + li) * 32 + lg * 8);

    const f32x4 z4 = (f32x4){0.f, 0.f, 0.f, 0.f};
    f32x4 acc[4][4];
    #pragma unroll
    for (int ct = 0; ct < 4; ++ct)
        #pragma unroll
        for (int is = 0; is < 4; ++is) acc[ct][is] = z4;

    float lsum[4] = {0.f, 0.f, 0.f, 0.f};

    const unsigned short* Kb = Kt + (size_t)b * HW * 32;
    const unsigned short* Vw = Vb + ((size_t)b * CC + w * 64) * HW;

    // QK + softmax for one tile; fills pk0/pk1 (packed bf16 P quads)
    auto qk_soft = [&](int j0, unsigned int* pk0, unsigned int* pk1) {
        f32x4 S[4];
        #pragma unroll
        for (int j2 = 0; j2 < 4; ++j2) {
            bf16x8 bk = *(const bf16x8*)(Kb + (size_t)(j0 + j2 * 16 + li) * 32 + lg * 8);
            S[j2] = __builtin_amdgcn_mfma_f32_16x16x32_bf16(aq, bk, z4, 0, 0, 0);
        }
        #pragma unroll
        for (int r = 0; r < 4; ++r) {
            float p0 = __builtin_amdgcn_exp2f(S[0][r]);
            float p1 = __builtin_amdgcn_exp2f(S[1][r]);
            float p2 = __builtin_amdgcn_exp2f(S[2][r]);
            float p3 = __builtin_amdgcn_exp2f(S[3][r]);
            lsum[r] += (p0 + p1) + (p2 + p3);
            asm("v_cvt_pk_bf16_f32 %0, %1, %2" : "=v"(pk0[r]) : "v"(p0), "v"(p1));
            asm("v_cvt_pk_bf16_f32 %0, %1, %2" : "=v"(pk1[r]) : "v"(p2), "v"(p3));
        }
    };

    auto write_ps = [&](int rbase, const unsigned int* pk0, const unsigned int* pk1) {
        #pragma unroll
        for (int r = 0; r < 4; ++r) {
            const int row = rbase + w * 16 + lg * 4 + r;
            Ps[row][li]      = (unsigned short)pk0[r];
            Ps[row][16 + li] = (unsigned short)(pk0[r] >> 16);
            Ps[row][32 + li] = (unsigned short)pk1[r];
            Ps[row][48 + li] = (unsigned short)(pk1[r] >> 16);
        }
    };

    auto pv = [&](int rbase, const bf16x8 vf[4][2]) {
        bf16x8 bp[4][2];
        #pragma unroll
        for (int is = 0; is < 4; ++is)
            #pragma unroll
            for (int ks = 0; ks < 2; ++ks)
                bp[is][ks] = *(const bf16x8*)(&Ps[rbase + is * 16 + li][ks * 32 + lg * 8]);
        #pragma unroll
        for (int ct = 0; ct < 4; ++ct)
            #pragma unroll
            for (int is = 0; is < 4; ++is) {
                acc[ct][is] = __builtin_amdgcn_mfma_f32_16x16x32_bf16(
                    vf[ct][0], bp[is][0], acc[ct][is], 0, 0, 0);
                acc[ct][is] = __builtin_amdgcn_mfma_f32_16x16x32_bf16(
                    vf[ct][1], bp[is][1], acc[ct][is], 0, 0, 0);
            }
    };

    int jt = 0;
    for (; jt + 2 <= NJT; jt += 2) {
        const int j0a = jt * 64, j0b = j0a + 64;

        // V fragments for BOTH tiles, issued first (latency under QK+softmax)
        bf16x8 vfa[4][2], vfb[4][2];
        #pragma unroll
        for (int ct = 0; ct < 4; ++ct) {
            const unsigned short* vr = Vw + (size_t)(ct * 16 + li) * HW;
            vfa[ct][0] = *(const bf16x8*)(vr + j0a + lg * 8);
            vfa[ct][1] = *(const bf16x8*)(vr + j0a + 32 + lg * 8);
            vfb[ct][0] = *(const bf16x8*)(vr + j0b + lg * 8);
            vfb[ct][1] = *(const bf16x8*)(vr + j0b + 32 + lg * 8);
        }

        unsigned int pk0a[4], pk1a[4], pk0b[4], pk1b[4];
        qk_soft(j0a, pk0a, pk1a);
        qk_soft(j0b, pk0b, pk1b);

        __syncthreads();  // prev pair's PV reads complete
        write_ps(0, pk0a, pk1a);
        write_ps(64, pk0b, pk1b);
        __syncthreads();  // both halves ready

        pv(0, vfa);
        pv(64, vfb);
    }

    // tail (NJT odd -> exactly one tile left)
    if (jt < NJT) {
        const int j0 = jt * 64;
        bf16x8 vf[4][2];
        #pragma unroll
        for (int ct = 0; ct < 4; ++ct) {
            const unsigned short* vr = Vw + (size_t)(ct * 16 + li) * HW;
            vf[ct][0] = *(const bf16x8*)(vr + j0 + lg * 8);
            vf[ct][1] = *(const bf16x8*)(vr + j0 + 32 + lg * 8);
        }
        unsigned int pk0[4], pk1[4];
        qk_soft(j0, pk0, pk1);
        __syncthreads();
        write_ps(0, pk0, pk1);
        __syncthreads();
        pv(0, vf);
    }

    // row-sum reduce over the 16 li lanes (j-distribution), once
    #pragma unroll
    for (int r = 0; r < 4; ++r) {
        float s = lsum[r];
        #pragma unroll
        for (int off = 1; off < 16; off <<= 1) s += __shfl_xor(s, off);
        if (li == 0) lls[w * 16 + lg * 4 + r] = s;
    }
    __syncthreads();

    float invl[4];
    #pragma unroll
    for (int is = 0; is < 4; ++is) invl[is] = 1.f / lls[is * 16 + li];

    #pragma unroll
    for (int ct = 0; ct < 4; ++ct)
        #pragma unroll
        for (int is = 0; is < 4; ++is)
            #pragma unroll
            for (int r = 0; r < 4; ++r) {
                int c = w * 64 + ct * 16 + lg * 4 + r;
                ATTb[((size_t)b * (4 * CC) + g * CC + c) * HW + i0 + is * 16 + li] =
                    f2bf(acc[ct][is][r] * invl[is]);
            }
}

// ---------------------------------------------------------------------------
// MFMA projection: out[b][co][i] = sum_{cin<1024} wproj[co][cin]*ATT[cin][i]+x.
// grid (HW/32, B), block 256 (4 waves, wave = 64-co strip).
// ---------------------------------------------------------------------------
__global__ __launch_bounds__(256) void gemm_proj(
    const unsigned short* __restrict__ ATTb, const unsigned short* __restrict__ Wpb,
    const float* __restrict__ x, float* __restrict__ out) {
    const int b = blockIdx.y;
    const int i0 = blockIdx.x * 32;
    const int t = threadIdx.x;
    const int lane = t & 63;
    const int w = t >> 6;
    const int lg = lane >> 4;
    const int li = lane & 15;

    __shared__ __align__(16) unsigned short As[32][72];  // [i][cin-chunk]

    const f32x4 z4 = (f32x4){0.f, 0.f, 0.f, 0.f};
    f32x4 acc[4][2];
    #pragma unroll
    for (int ct = 0; ct < 4; ++ct) { acc[ct][0] = z4; acc[ct][1] = z4; }

    for (int k0 = 0; k0 < 1024; k0 += 64) {
        __syncthreads();
        {
            int row = t >> 2, seg = t & 3;
            uint4 v = *(const uint4*)(
                ATTb + ((size_t)b * 1024 + k0 + row) * HW + i0 + seg * 8);
            const unsigned short* sv = (const unsigned short*)&v;
            #pragma unroll
            for (int u = 0; u < 8; ++u) As[seg * 8 + u][row] = sv[u];
        }
        __syncthreads();

        #pragma unroll
        for (int k2 = 0; k2 < 2; ++k2) {
            bf16x8 afr[2];
            #pragma unroll
            for (int is = 0; is < 2; ++is)
                afr[is] = *(const bf16x8*)(&As[is * 16 + li][k2 * 32 + lg * 8]);
            #pragma unroll
            for (int ct = 0; ct < 4; ++ct) {
                bf16x8 wf = *(const bf16x8*)(
                    Wpb + (size_t)(w * 64 + ct * 16 + li) * 1024 + k0 + k2 * 32 + lg * 8);
                #pragma unroll
                for (int is = 0; is < 2; ++is)
                    acc[ct][is] = __builtin_amdgcn_mfma_f32_16x16x32_bf16(
                        wf, afr[is], acc[ct][is], 0, 0, 0);
            }
        }
    }

    #pragma unroll
    for (int ct = 0; ct < 4; ++ct)
        #pragma unroll
        for (int is = 0; is < 2; ++is)
            #pragma unroll
            for (int r = 0; r < 4; ++r) {
                int co = w * 64 + ct * 16 + lg * 4 + r;
                size_t o = ((size_t)b * CC + co) * HW + i0 + is * 16 + li;
                out[o] = acc[ct][is][r] + x[o];
            }
}

// ---------------------------------------------------------------------------
// BatchNorm
// ---------------------------------------------------------------------------
__global__ __launch_bounds__(256) void bnstats(
    const float* __restrict__ out, float* __restrict__ mean,
    float* __restrict__ rstd) {
    const int c = blockIdx.x;
    float s = 0.f, s2 = 0.f;
    for (int e = threadIdx.x; e < BB * HW; e += 256) {
        int b = e / HW, i = e - b * HW;
        float v = out[((size_t)b * CC + c) * HW + i];
        s += v; s2 += v * v;
    }
    __shared__ float rs[256], rs2[256];
    rs[threadIdx.x] = s; rs2[threadIdx.x] = s2;
    __syncthreads();
    for (int st = 128; st > 0; st >>= 1) {
        if (threadIdx.x < st) {
            rs[threadIdx.x] += rs[threadIdx.x + st];
            rs2[threadIdx.x] += rs2[threadIdx.x + st];
        }
        __syncthreads();
    }
    if (threadIdx.x == 0) {
        const float n = (float)(BB * HW);
        float m = rs[0] / n;
        float var = rs2[0] / n - m * m;
        mean[c] = m;
        rstd[c] = rsqrtf(var + 1e-5f);
    }
}

__global__ __launch_bounds__(256) void bnapply(
    float* __restrict__ out, const float* __restrict__ mean,
    const float* __restrict__ rstd, const float* __restrict__ gamma,
    const float* __restrict__ beta) {
    size_t idx = (size_t)blockIdx.x * 256 + threadIdx.x;
    if (idx < (size_t)BB * CC * HW) {
        int c = (int)((idx / HW) % CC);
        out[idx] = (out[idx] - mean[c]) * rstd[c] * gamma[c] + beta[c];
    }
}

// ---------------------------------------------------------------------------
extern "C" void kernel_launch(void* const* d_in, const int* in_sizes, int n_in,
                              void* d_out, int out_size, void* d_ws, size_t ws_size,
                              hipStream_t stream) {
    const float* x     = (const float*)d_in[0];
    const float* wq1   = (const float*)d_in[1];
    const float* wq3   = (const float*)d_in[2];
    const float* wq5   = (const float*)d_in[3];
    const float* wq7   = (const float*)d_in[4];
    const float* wk    = (const float*)d_in[5];
    const float* wv    = (const float*)d_in[6];
    const float* wproj = (const float*)d_in[7];
    const float* gamma = (const float*)d_in[8];
    const float* beta  = (const float*)d_in[9];
    float* out = (float*)d_out;

    unsigned short* ATTb = (unsigned short*)d_ws;            // [B][1024][HW]
    unsigned short* Kt   = ATTb + (size_t)BB * 4 * CC * HW;  // [B][HW][32]
    unsigned short* Qt   = Kt + (size_t)BB * HW * 32;        // 4 x [B][HW][32]
    unsigned short* Vb   = Qt + (size_t)4 * BB * HW * 32;    // [B][C][HW]
    unsigned short* xT   = Vb + (size_t)BB * CC * HW;        // [B][HW][256]
    unsigned short* Wb3  = xT + (size_t)BB * HW * CC;        // [9][32][256]
    unsigned short* Wb5  = Wb3 + (size_t)9 * 32 * 256;
    unsigned short* Wb7  = Wb5 + (size_t)25 * 32 * 256;
    unsigned short* Wpb  = Wb7 + (size_t)49 * 32 * 256;      // [256][1024]
    unsigned short* Wkq  = Wpb + (size_t)256 * 1024;         // [2][32][256]
    unsigned short* Wvb  = Wkq + (size_t)2 * 32 * 256;       // [256][256]
    float* mean = (float*)(Wvb + (size_t)256 * 256);
    float* rstd = mean + CC;

    dim3 blk(256);

    // prep: all weights (one launch) + x transpose
    prep_weights<<<dim3(4000), blk, 0, stream>>>(
        wq3, wq5, wq7, wproj, wk, wq1, wv, Wb3, Wb5, Wb7, Wpb, Wkq, Wvb);
    transpose_x<<<dim3(HW / 32, CC / 32, BB), blk, 0, stream>>>(x, xT);

    // K + Q1 (MFMA, no LDS), V (MFMA, no LDS)
    qk32_mfma<<<dim3(HW / 64, BB, 2), blk, 0, stream>>>(xT, Wkq, Kt, Qt);
    v_mfma<<<dim3(HW / 32, BB), blk, 0, stream>>>(xT, Wvb, Vb);

    // q3/q5/q7 fused MFMA im2col convs
    qconv_all<<<dim3(HW / 64, BB, 3), blk, 0, stream>>>(xT, Wb3, Wb5, Wb7, Qt);

    // MFMA flash attention v5 (2 j-tiles per barrier pair), all 4 branches
    flashmfma<<<dim3(HW / 64, BB, 4), blk, 0, stream>>>(Qt, Kt, Vb, ATTb);

    // MFMA projection + residual -> d_out (pre-BN, fp32)
    gemm_proj<<<dim3(HW / 32, BB), blk, 0, stream>>>(ATTb, Wpb, x, out);

    // BatchNorm
    bnstats<<<dim3(CC), blk, 0, stream>>>(out, mean, rstd);
    bnapply<<<dim3((BB * CC * HW + 255) / 256), blk, 0, stream>>>(out, mean, rstd, gamma, beta);
}